// Round 7
// baseline (12061.048 us; speedup 1.0000x reference)
//
#include <hip/hip_runtime.h>
#include <stdint.h>

#define T_TOTAL 32
#define BATCH   1024
#define INDIM   784
#define HDIM    4096
#define OUTDIM  10
#define BH      (BATCH * HDIM)      // 4,194,304
#define WORDS_PER_T (BH / 64)       // 65,536 u64 words per timestep
#define NKSTEP  49                  // 784 / 16
#define LBUF    2112                // 16*132 floats per buffer

// ---------------- W2 transpose: W2[10][4096] -> W2T[4096][10] ----------------
__global__ void k_transpose_w2(const float* __restrict__ W2, float* __restrict__ W2T) {
    int i = blockIdx.x * 256 + threadIdx.x;
    if (i < HDIM * OUTDIM) {
        int h = i / OUTDIM, o = i % OUTDIM;
        W2T[i] = W2[o * HDIM + h];
    }
}

// ---------------- fp32 GEMM: Z[m][n] = sum_k A[m][k]*B[n][k], ascending-k fma ----------------
// Round-6 geometry (BM=BN=128, BK=16, 256 thr, 8x8 micro-tile, 2-way-max LDS aliasing)
// + DOUBLE-BUFFERED LDS: one barrier per K-step; staging ds_writes and next-step
// global loads overlap the fma phase. Race-free: a wave at write(s+2) (same buffer
// as s) passed barrier(s+1), which every wave reaches only after fma(s).
// Accumulation: ONE fma per k, k ascending -> bitwise identical to OpenBLAS sgemm
// (empirically required: rounds 1/6 absmax 0.0, any reorder flips a spike).
__global__ __launch_bounds__(256, 4) void k_gemm_f32(const float* __restrict__ A,
                                                     const float* __restrict__ B,
                                                     float* __restrict__ Z) {
    __shared__ float As[2 * LBUF];   // [buf][k][m], 16.9 KB
    __shared__ float Bs[2 * LBUF];   // [buf][k][n], 16.9 KB

    // XCD-bijective swizzle (gridDim.x = (Mc/128)*32, always % 8 == 0)
    const int cpx = gridDim.x >> 3;
    const int swz = (blockIdx.x & 7) * cpx + (blockIdx.x >> 3);
    const int nbm = gridDim.x >> 5;          // m-blocks (Mc/128)
    const int bm  = swz % nbm;               // consecutive swz share bn -> B panel stays hot
    const int bn  = swz / nbm;

    const int tid = threadIdx.x;
    const int tc  = tid & 15;                // n-dir
    const int tr  = tid >> 4;                // m-dir

    const float* Ag = A + (size_t)bm * 128 * INDIM;
    const float* Bg = B + (size_t)bn * 128 * INDIM;

    // staging: thread covers rows r0 and r0+64, k-quad kq
    const int r0 = tid >> 2;                 // 0..63
    const int r1 = r0 + 64;
    const int kq = (tid & 3) << 2;           // 0,4,8,12
    float4 ra0, ra1, rb0, rb1;

    // prefetch k-step 0
    ra0 = *(const float4*)(Ag + (size_t)r0 * INDIM + kq);
    ra1 = *(const float4*)(Ag + (size_t)r1 * INDIM + kq);
    rb0 = *(const float4*)(Bg + (size_t)r0 * INDIM + kq);
    rb1 = *(const float4*)(Bg + (size_t)r1 * INDIM + kq);

    float4 acc[8][2];
#pragma unroll
    for (int i = 0; i < 8; ++i)
#pragma unroll
        for (int g = 0; g < 2; ++g) acc[i][g] = (float4){0.f, 0.f, 0.f, 0.f};

    int lo = 0;   // LDS buffer offset toggle (0 / LBUF), wave-uniform
    for (int s = 0; s < NKSTEP; ++s) {
        // write staged regs -> buf[lo] (overlaps other waves' fma on buf[lo^LBUF])
        As[lo + (kq + 0) * 132 + r0] = ra0.x;
        As[lo + (kq + 1) * 132 + r0] = ra0.y;
        As[lo + (kq + 2) * 132 + r0] = ra0.z;
        As[lo + (kq + 3) * 132 + r0] = ra0.w;
        As[lo + (kq + 0) * 132 + r1] = ra1.x;
        As[lo + (kq + 1) * 132 + r1] = ra1.y;
        As[lo + (kq + 2) * 132 + r1] = ra1.z;
        As[lo + (kq + 3) * 132 + r1] = ra1.w;
        Bs[lo + (kq + 0) * 132 + r0] = rb0.x;
        Bs[lo + (kq + 1) * 132 + r0] = rb0.y;
        Bs[lo + (kq + 2) * 132 + r0] = rb0.z;
        Bs[lo + (kq + 3) * 132 + r0] = rb0.w;
        Bs[lo + (kq + 0) * 132 + r1] = rb1.x;
        Bs[lo + (kq + 1) * 132 + r1] = rb1.y;
        Bs[lo + (kq + 2) * 132 + r1] = rb1.z;
        Bs[lo + (kq + 3) * 132 + r1] = rb1.w;
        __syncthreads();    // buf[lo] complete; ONE barrier per K-step

        // issue next k-step's global loads; they land under the fma phase
        if (s + 1 < NKSTEP) {
            const int kn = (s + 1) * 16 + kq;
            ra0 = *(const float4*)(Ag + (size_t)r0 * INDIM + kn);
            ra1 = *(const float4*)(Ag + (size_t)r1 * INDIM + kn);
            rb0 = *(const float4*)(Bg + (size_t)r0 * INDIM + kn);
            rb1 = *(const float4*)(Bg + (size_t)r1 * INDIM + kn);
        }

        // fma phase: 16 kk x 64 fma/thread, k ascending
        __builtin_amdgcn_s_setprio(1);
#pragma unroll
        for (int kk = 0; kk < 16; ++kk) {
            const float* ap = &As[lo + kk * 132 + tr * 8];
            float4 a0 = *(const float4*)ap;          // broadcast (4 addrs/wave)
            float4 a1 = *(const float4*)(ap + 4);
            const float* bp = &Bs[lo + kk * 132 + tc * 4];
            float4 b0 = *(const float4*)bp;          // 2-way aliasing: free
            float4 b1 = *(const float4*)(bp + 64);
            float a[8] = {a0.x, a0.y, a0.z, a0.w, a1.x, a1.y, a1.z, a1.w};
#pragma unroll
            for (int i = 0; i < 8; ++i) {
                acc[i][0].x = fmaf(a[i], b0.x, acc[i][0].x);
                acc[i][0].y = fmaf(a[i], b0.y, acc[i][0].y);
                acc[i][0].z = fmaf(a[i], b0.z, acc[i][0].z);
                acc[i][0].w = fmaf(a[i], b0.w, acc[i][0].w);
                acc[i][1].x = fmaf(a[i], b1.x, acc[i][1].x);
                acc[i][1].y = fmaf(a[i], b1.y, acc[i][1].y);
                acc[i][1].z = fmaf(a[i], b1.z, acc[i][1].z);
                acc[i][1].w = fmaf(a[i], b1.w, acc[i][1].w);
            }
        }
        __builtin_amdgcn_s_setprio(0);
        lo ^= LBUF;
    }

    const int m0 = bm * 128 + tr * 8;
    const int n0 = bn * 128 + tc * 4;
#pragma unroll
    for (int i = 0; i < 8; ++i) {
        *(float4*)(Z + (size_t)(m0 + i) * HDIM + n0)      = acc[i][0];
        *(float4*)(Z + (size_t)(m0 + i) * HDIM + n0 + 64) = acc[i][1];
    }
}

// ---------------- Layer-1 IF recurrence (ballot -> bitmask) ----------------
__global__ __launch_bounds__(256) void k_layer1(const float* __restrict__ Z,
                                                float* __restrict__ v1s,
                                                uint64_t* __restrict__ S1,
                                                int Tc, int first) {
    const size_t i = (size_t)blockIdx.x * 256 + threadIdx.x;
    float v = first ? 0.0f : v1s[i];
    const int lane = threadIdx.x & 63;
    const size_t word = i >> 6;
    for (int t = 0; t < Tc; ++t) {
        float z = Z[(size_t)t * BH + i];
        v += z;
        bool s = (v >= 1.0f);
        unsigned long long m = __ballot(s);
        if (lane == 0) S1[(size_t)t * WORDS_PER_T + word] = m;
        if (s) v = 0.0f;
    }
    v1s[i] = v;
}

// ---------------- Layer-2 partial sums from spike bitmask ----------------
__global__ __launch_bounds__(256) void k_layer2_partial(const uint64_t* __restrict__ S1,
                                                        const float* __restrict__ W2T,
                                                        float* __restrict__ part,
                                                        int rowsTotal) {
    __shared__ float w[1024][10];   // 40 KB
    const int hs = blockIdx.y;
    for (int i = threadIdx.x; i < 1024 * 10; i += 256)
        w[i / 10][i % 10] = W2T[hs * 1024 * 10 + i];
    __syncthreads();

    const int row = blockIdx.x * 256 + threadIdx.x;
    const uint64_t* wp = S1 + (size_t)row * 64 + hs * 16;
    float acc[10] = {};
    for (int wi = 0; wi < 16; ++wi) {
        uint64_t m = wp[wi];
        while (m) {
            int bit = __builtin_ctzll(m);
            m &= m - 1;
            int hl = wi * 64 + bit;
#pragma unroll
            for (int o = 0; o < 10; ++o) acc[o] += w[hl][o];
        }
    }
    float* p = part + ((size_t)hs * rowsTotal + row) * 10;
#pragma unroll
    for (int o = 0; o < 10; ++o) p[o] = acc[o];
}

// ---------------- Layer-2 IF recurrence + spike record ----------------
__global__ __launch_bounds__(256) void k_layer2_rec(const float* __restrict__ part,
                                                    float* __restrict__ v2s,
                                                    float* __restrict__ recs,
                                                    float* __restrict__ out,
                                                    int Tc, int first, int last) {
    const int i = blockIdx.x * 256 + threadIdx.x;
    if (i >= BATCH * OUTDIM) return;
    float v   = first ? 0.0f : v2s[i];
    float rec = first ? 0.0f : recs[i];
    const int rowsTotal = Tc * BATCH;
    const int b = i / OUTDIM, o = i % OUTDIM;
    for (int t = 0; t < Tc; ++t) {
        const int r = t * BATCH + b;
        float sig = 0.0f;
#pragma unroll
        for (int hs = 0; hs < 4; ++hs)
            sig += part[((size_t)hs * rowsTotal + r) * 10 + o];
        v += sig;
        bool s = (v >= 1.0f);
        rec += s ? 1.0f : 0.0f;
        if (s) v = 0.0f;
    }
    v2s[i] = v;
    recs[i] = rec;
    if (last) out[i] = rec;
}

// ---------------- launch ----------------
extern "C" void kernel_launch(void* const* d_in, const int* in_sizes, int n_in,
                              void* d_out, int out_size, void* d_ws, size_t ws_size,
                              hipStream_t stream) {
    (void)in_sizes; (void)n_in; (void)out_size;
    const float* x  = (const float*)d_in[0];   // [32][1024][784]
    const float* W1 = (const float*)d_in[1];   // [4096][784]
    const float* W2 = (const float*)d_in[2];   // [10][4096]
    float* out = (float*)d_out;                // [1024][10]

    const size_t szW2T = (size_t)HDIM * OUTDIM * 4;          // 163,840
    const size_t szV1  = (size_t)BH * 4;                     // 16,777,216
    const size_t szV2  = (size_t)BATCH * OUTDIM * 4;         // 40,960
    const size_t base  = szW2T + szV1 + 2 * szV2;
    const size_t perT  = (size_t)BH * 4                      // Z per step
                       + (size_t)WORDS_PER_T * 8             // S1 per step
                       + (size_t)4 * BATCH * OUTDIM * 4;     // part per step
    int Tc = 1;
    const int cands[6] = {32, 16, 8, 4, 2, 1};
    for (int ci = 0; ci < 6; ++ci)
        if (base + (size_t)cands[ci] * perT <= ws_size) { Tc = cands[ci]; break; }
    const int Mc = Tc * BATCH;

    char* p = (char*)d_ws;
    float*    W2T  = (float*)p;     p += szW2T;
    float*    v1s  = (float*)p;     p += szV1;
    float*    v2s  = (float*)p;     p += szV2;
    float*    recs = (float*)p;     p += szV2;
    float*    Z    = (float*)p;     p += (size_t)Tc * BH * 4;
    uint64_t* S1   = (uint64_t*)p;  p += (size_t)Tc * WORDS_PER_T * 8;
    float*    part = (float*)p;

    k_transpose_w2<<<(HDIM * OUTDIM + 255) / 256, 256, 0, stream>>>(W2, W2T);

    const int nch = T_TOTAL / Tc;
    for (int c = 0; c < nch; ++c) {
        const float* Ac = x + (size_t)c * Mc * INDIM;
        k_gemm_f32<<<(Mc / 128) * (HDIM / 128), 256, 0, stream>>>(Ac, W1, Z);
        k_layer1<<<BH / 256, 256, 0, stream>>>(Z, v1s, S1, Tc, c == 0);
        k_layer2_partial<<<dim3(Tc * 4, 4), 256, 0, stream>>>(S1, W2T, part, Tc * BATCH);
        k_layer2_rec<<<(BATCH * OUTDIM + 255) / 256, 256, 0, stream>>>(
            part, v2s, recs, out, Tc, c == 0, c == nch - 1);
    }
}

// Round 8
// 2494.758 us; speedup vs baseline: 4.8346x; 4.8346x over previous
//
#include <hip/hip_runtime.h>
#include <stdint.h>

#define T_TOTAL 32
#define BATCH   1024
#define INDIM   784
#define HDIM    4096
#define OUTDIM  10
#define BH      (BATCH * HDIM)      // 4,194,304
#define WORDS_PER_T (BH / 64)       // 65,536 u64 words per timestep
#define NKSTEP  49                  // 784 / 16
#define LBUF    2112                // 16*132 floats per buffer

// ---------------- W2 transpose: W2[10][4096] -> W2T[4096][10] ----------------
__global__ void k_transpose_w2(const float* __restrict__ W2, float* __restrict__ W2T) {
    int i = blockIdx.x * 256 + threadIdx.x;
    if (i < HDIM * OUTDIM) {
        int h = i / OUTDIM, o = i % OUTDIM;
        W2T[i] = W2[o * HDIM + h];
    }
}

// ---------------- fp32 GEMM: Z[m][n] = sum_k A[m][k]*B[n][k], ascending-k fma ----------------
// Round-6 geometry (BM=BN=128, BK=16, 256 thr, 8x8 micro-tile, 2-way-max LDS aliasing)
// + double-buffered LDS: ONE barrier per K-step; staging ds_writes and next-step
// global loads overlap the fma phase on the other buffer. Race-free: a wave at
// write(s+2) (same buffer as s) passed barrier(s+1), which follows every wave's fma(s).
// NO __launch_bounds__ min-waves arg (round 7: ",4" forced a 64-VGPR budget and
// spilled the 64-reg accumulator -> 30 GB scratch traffic, 5x regression).
// Accumulation: ONE fma per k, k ascending -> bitwise identical to OpenBLAS sgemm.
__global__ __launch_bounds__(256) void k_gemm_f32(const float* __restrict__ A,
                                                  const float* __restrict__ B,
                                                  float* __restrict__ Z) {
    __shared__ float As[2 * LBUF];   // [buf][k][m], 16.9 KB
    __shared__ float Bs[2 * LBUF];   // [buf][k][n], 16.9 KB

    // XCD-bijective swizzle (gridDim.x = (Mc/128)*32, always % 8 == 0)
    const int cpx = gridDim.x >> 3;
    const int swz = (blockIdx.x & 7) * cpx + (blockIdx.x >> 3);
    const int nbm = gridDim.x >> 5;          // m-blocks (Mc/128)
    const int bm  = swz % nbm;               // consecutive swz share bn -> B panel stays hot
    const int bn  = swz / nbm;

    const int tid = threadIdx.x;
    const int tc  = tid & 15;                // n-dir
    const int tr  = tid >> 4;                // m-dir

    const float* Ag = A + (size_t)bm * 128 * INDIM;
    const float* Bg = B + (size_t)bn * 128 * INDIM;

    // staging: thread covers rows r0 and r0+64, k-quad kq
    const int r0 = tid >> 2;                 // 0..63
    const int r1 = r0 + 64;
    const int kq = (tid & 3) << 2;           // 0,4,8,12
    float4 ra0, ra1, rb0, rb1;

    // prefetch k-step 0
    ra0 = *(const float4*)(Ag + (size_t)r0 * INDIM + kq);
    ra1 = *(const float4*)(Ag + (size_t)r1 * INDIM + kq);
    rb0 = *(const float4*)(Bg + (size_t)r0 * INDIM + kq);
    rb1 = *(const float4*)(Bg + (size_t)r1 * INDIM + kq);

    float4 acc[8][2];
#pragma unroll
    for (int i = 0; i < 8; ++i)
#pragma unroll
        for (int g = 0; g < 2; ++g) acc[i][g] = (float4){0.f, 0.f, 0.f, 0.f};

    int lo = 0;   // LDS buffer offset toggle (0 / LBUF), wave-uniform
    for (int s = 0; s < NKSTEP; ++s) {
        // write staged regs -> buf[lo] (overlaps other waves' fma on buf[lo^LBUF])
        As[lo + (kq + 0) * 132 + r0] = ra0.x;
        As[lo + (kq + 1) * 132 + r0] = ra0.y;
        As[lo + (kq + 2) * 132 + r0] = ra0.z;
        As[lo + (kq + 3) * 132 + r0] = ra0.w;
        As[lo + (kq + 0) * 132 + r1] = ra1.x;
        As[lo + (kq + 1) * 132 + r1] = ra1.y;
        As[lo + (kq + 2) * 132 + r1] = ra1.z;
        As[lo + (kq + 3) * 132 + r1] = ra1.w;
        Bs[lo + (kq + 0) * 132 + r0] = rb0.x;
        Bs[lo + (kq + 1) * 132 + r0] = rb0.y;
        Bs[lo + (kq + 2) * 132 + r0] = rb0.z;
        Bs[lo + (kq + 3) * 132 + r0] = rb0.w;
        Bs[lo + (kq + 0) * 132 + r1] = rb1.x;
        Bs[lo + (kq + 1) * 132 + r1] = rb1.y;
        Bs[lo + (kq + 2) * 132 + r1] = rb1.z;
        Bs[lo + (kq + 3) * 132 + r1] = rb1.w;
        __syncthreads();    // buf[lo] complete; ONE barrier per K-step

        // issue next k-step's global loads; they land under the fma phase
        if (s + 1 < NKSTEP) {
            const int kn = (s + 1) * 16 + kq;
            ra0 = *(const float4*)(Ag + (size_t)r0 * INDIM + kn);
            ra1 = *(const float4*)(Ag + (size_t)r1 * INDIM + kn);
            rb0 = *(const float4*)(Bg + (size_t)r0 * INDIM + kn);
            rb1 = *(const float4*)(Bg + (size_t)r1 * INDIM + kn);
        }

        // fma phase: 16 kk x 64 fma/thread, k ascending
#pragma unroll
        for (int kk = 0; kk < 16; ++kk) {
            const float* ap = &As[lo + kk * 132 + tr * 8];
            float4 a0 = *(const float4*)ap;          // broadcast (4 addrs/wave)
            float4 a1 = *(const float4*)(ap + 4);
            const float* bp = &Bs[lo + kk * 132 + tc * 4];
            float4 b0 = *(const float4*)bp;          // 2-way aliasing: free
            float4 b1 = *(const float4*)(bp + 64);
            float a[8] = {a0.x, a0.y, a0.z, a0.w, a1.x, a1.y, a1.z, a1.w};
#pragma unroll
            for (int i = 0; i < 8; ++i) {
                acc[i][0].x = fmaf(a[i], b0.x, acc[i][0].x);
                acc[i][0].y = fmaf(a[i], b0.y, acc[i][0].y);
                acc[i][0].z = fmaf(a[i], b0.z, acc[i][0].z);
                acc[i][0].w = fmaf(a[i], b0.w, acc[i][0].w);
                acc[i][1].x = fmaf(a[i], b1.x, acc[i][1].x);
                acc[i][1].y = fmaf(a[i], b1.y, acc[i][1].y);
                acc[i][1].z = fmaf(a[i], b1.z, acc[i][1].z);
                acc[i][1].w = fmaf(a[i], b1.w, acc[i][1].w);
            }
        }
        lo ^= LBUF;
    }

    const int m0 = bm * 128 + tr * 8;
    const int n0 = bn * 128 + tc * 4;
#pragma unroll
    for (int i = 0; i < 8; ++i) {
        *(float4*)(Z + (size_t)(m0 + i) * HDIM + n0)      = acc[i][0];
        *(float4*)(Z + (size_t)(m0 + i) * HDIM + n0 + 64) = acc[i][1];
    }
}

// ---------------- Layer-1 IF recurrence (ballot -> bitmask) ----------------
__global__ __launch_bounds__(256) void k_layer1(const float* __restrict__ Z,
                                                float* __restrict__ v1s,
                                                uint64_t* __restrict__ S1,
                                                int Tc, int first) {
    const size_t i = (size_t)blockIdx.x * 256 + threadIdx.x;
    float v = first ? 0.0f : v1s[i];
    const int lane = threadIdx.x & 63;
    const size_t word = i >> 6;
    for (int t = 0; t < Tc; ++t) {
        float z = Z[(size_t)t * BH + i];
        v += z;
        bool s = (v >= 1.0f);
        unsigned long long m = __ballot(s);
        if (lane == 0) S1[(size_t)t * WORDS_PER_T + word] = m;
        if (s) v = 0.0f;
    }
    v1s[i] = v;
}

// ---------------- Layer-2 partial sums from spike bitmask ----------------
__global__ __launch_bounds__(256) void k_layer2_partial(const uint64_t* __restrict__ S1,
                                                        const float* __restrict__ W2T,
                                                        float* __restrict__ part,
                                                        int rowsTotal) {
    __shared__ float w[1024][10];   // 40 KB
    const int hs = blockIdx.y;
    for (int i = threadIdx.x; i < 1024 * 10; i += 256)
        w[i / 10][i % 10] = W2T[hs * 1024 * 10 + i];
    __syncthreads();

    const int row = blockIdx.x * 256 + threadIdx.x;
    const uint64_t* wp = S1 + (size_t)row * 64 + hs * 16;
    float acc[10] = {};
    for (int wi = 0; wi < 16; ++wi) {
        uint64_t m = wp[wi];
        while (m) {
            int bit = __builtin_ctzll(m);
            m &= m - 1;
            int hl = wi * 64 + bit;
#pragma unroll
            for (int o = 0; o < 10; ++o) acc[o] += w[hl][o];
        }
    }
    float* p = part + ((size_t)hs * rowsTotal + row) * 10;
#pragma unroll
    for (int o = 0; o < 10; ++o) p[o] = acc[o];
}

// ---------------- Layer-2 IF recurrence + spike record ----------------
__global__ __launch_bounds__(256) void k_layer2_rec(const float* __restrict__ part,
                                                    float* __restrict__ v2s,
                                                    float* __restrict__ recs,
                                                    float* __restrict__ out,
                                                    int Tc, int first, int last) {
    const int i = blockIdx.x * 256 + threadIdx.x;
    if (i >= BATCH * OUTDIM) return;
    float v   = first ? 0.0f : v2s[i];
    float rec = first ? 0.0f : recs[i];
    const int rowsTotal = Tc * BATCH;
    const int b = i / OUTDIM, o = i % OUTDIM;
    for (int t = 0; t < Tc; ++t) {
        const int r = t * BATCH + b;
        float sig = 0.0f;
#pragma unroll
        for (int hs = 0; hs < 4; ++hs)
            sig += part[((size_t)hs * rowsTotal + r) * 10 + o];
        v += sig;
        bool s = (v >= 1.0f);
        rec += s ? 1.0f : 0.0f;
        if (s) v = 0.0f;
    }
    v2s[i] = v;
    recs[i] = rec;
    if (last) out[i] = rec;
}

// ---------------- launch ----------------
extern "C" void kernel_launch(void* const* d_in, const int* in_sizes, int n_in,
                              void* d_out, int out_size, void* d_ws, size_t ws_size,
                              hipStream_t stream) {
    (void)in_sizes; (void)n_in; (void)out_size;
    const float* x  = (const float*)d_in[0];   // [32][1024][784]
    const float* W1 = (const float*)d_in[1];   // [4096][784]
    const float* W2 = (const float*)d_in[2];   // [10][4096]
    float* out = (float*)d_out;                // [1024][10]

    const size_t szW2T = (size_t)HDIM * OUTDIM * 4;          // 163,840
    const size_t szV1  = (size_t)BH * 4;                     // 16,777,216
    const size_t szV2  = (size_t)BATCH * OUTDIM * 4;         // 40,960
    const size_t base  = szW2T + szV1 + 2 * szV2;
    const size_t perT  = (size_t)BH * 4                      // Z per step
                       + (size_t)WORDS_PER_T * 8             // S1 per step
                       + (size_t)4 * BATCH * OUTDIM * 4;     // part per step
    int Tc = 1;
    const int cands[6] = {32, 16, 8, 4, 2, 1};
    for (int ci = 0; ci < 6; ++ci)
        if (base + (size_t)cands[ci] * perT <= ws_size) { Tc = cands[ci]; break; }
    const int Mc = Tc * BATCH;

    char* p = (char*)d_ws;
    float*    W2T  = (float*)p;     p += szW2T;
    float*    v1s  = (float*)p;     p += szV1;
    float*    v2s  = (float*)p;     p += szV2;
    float*    recs = (float*)p;     p += szV2;
    float*    Z    = (float*)p;     p += (size_t)Tc * BH * 4;
    uint64_t* S1   = (uint64_t*)p;  p += (size_t)Tc * WORDS_PER_T * 8;
    float*    part = (float*)p;

    k_transpose_w2<<<(HDIM * OUTDIM + 255) / 256, 256, 0, stream>>>(W2, W2T);

    const int nch = T_TOTAL / Tc;
    for (int c = 0; c < nch; ++c) {
        const float* Ac = x + (size_t)c * Mc * INDIM;
        k_gemm_f32<<<(Mc / 128) * (HDIM / 128), 256, 0, stream>>>(Ac, W1, Z);
        k_layer1<<<BH / 256, 256, 0, stream>>>(Z, v1s, S1, Tc, c == 0);
        k_layer2_partial<<<dim3(Tc * 4, 4), 256, 0, stream>>>(S1, W2T, part, Tc * BATCH);
        k_layer2_rec<<<(BATCH * OUTDIM + 255) / 256, 256, 0, stream>>>(
            part, v2s, recs, out, Tc, c == 0, c == nch - 1);
    }
}